// Round 2
// baseline (19571.733 us; speedup 1.0000x reference)
//
#include <hip/hip_runtime.h>
#include <math.h>

#define N_NODESC 50000
#define N_EDGESC 5000
#define NNZC     250000
#define IN_DIMC  256
#define OCC      512
#define NHC      8
#define DHC      64
#define EPSBN    1e-5f

// ---------------------------------------------------------------------------
// Generic fp32 GEMM: C[M,N] = A[M,K] @ B[K,N] (+bias) (gelu?) (+res)
// N, K multiples of 32 in this problem; M guarded.
// ---------------------------------------------------------------------------
__global__ __launch_bounds__(1024)
void gemm_kernel(const float* __restrict__ A, const float* __restrict__ B,
                 float* C, int M, int N, int K,
                 const float* __restrict__ bias, const float* res, int act)
{
    __shared__ float As[32][33];
    __shared__ float Bs[32][33];
    int tx = threadIdx.x, ty = threadIdx.y;
    int row = blockIdx.y * 32 + ty;
    int col = blockIdx.x * 32 + tx;
    float acc = 0.f;
    const float* arow = A + (size_t)row * K;
    for (int k0 = 0; k0 < K; k0 += 32) {
        As[ty][tx] = (row < M) ? arow[k0 + tx] : 0.f;
        Bs[ty][tx] = B[(size_t)(k0 + ty) * N + col];
        __syncthreads();
#pragma unroll
        for (int kk = 0; kk < 32; kk++)
            acc = fmaf(As[ty][kk], Bs[kk][tx], acc);
        __syncthreads();
    }
    if (row < M) {
        size_t o = (size_t)row * N + col;
        if (bias) acc += bias[col];
        if (act == 1) acc = 0.5f * acc * (1.f + erff(acc * 0.70710678118654752f));
        if (res)  acc += res[o];
        C[o] = acc;
    }
}

// ---------------------------------------------------------------------------
// Scores: s[i,h] = scale * dot(Q[qids[i],h,:], K[kids[i],h,:])  (d=64)
// Also atomicMax into per-segment max (order-preserving uint encoding).
// One 64-lane wave per nnz.
// ---------------------------------------------------------------------------
__device__ __forceinline__ unsigned f32_order(float f) {
    unsigned u = __float_as_uint(f);
    return (u & 0x80000000u) ? ~u : (u | 0x80000000u);
}
__device__ __forceinline__ float f32_unorder(unsigned u) {
    unsigned b = (u & 0x80000000u) ? (u & 0x7FFFFFFFu) : ~u;
    return __uint_as_float(b);
}

__global__ __launch_bounds__(64)
void score_kernel(const float* __restrict__ Qm, const int* __restrict__ qids,
                  const float* __restrict__ Km, const int* __restrict__ kids,
                  const int* __restrict__ segids,
                  float* __restrict__ sout, unsigned* __restrict__ segM)
{
    int i = blockIdx.x;
    int lane = threadIdx.x;
    const float* qp = Qm + (size_t)qids[i] * OCC;
    const float* kp = Km + (size_t)kids[i] * OCC;
    float prod[NHC];
#pragma unroll
    for (int j = 0; j < NHC; j++)
        prod[j] = qp[j * 64 + lane] * kp[j * 64 + lane];
#pragma unroll
    for (int j = 0; j < NHC; j++) {
        float v = prod[j];
        for (int o = 32; o > 0; o >>= 1) v += __shfl_xor(v, o, 64);
        prod[j] = v;
    }
    if (lane < NHC) {
        float s = 0.f;
#pragma unroll
        for (int j = 0; j < NHC; j++) if (lane == j) s = prod[j];  // keep in regs
        s *= 0.125f;  // 1/sqrt(64)
        sout[(size_t)i * NHC + lane] = s;
        atomicMax(segM + (size_t)segids[i] * NHC + lane, f32_order(s));
    }
}

// ---------------------------------------------------------------------------
// ex = exp(s - segmax[seg]);  atomicAdd segment sum.  In-place on s.
// ---------------------------------------------------------------------------
__global__ __launch_bounds__(256)
void expsum_kernel(float* __restrict__ s, const int* __restrict__ segids,
                   const unsigned* __restrict__ segM, float* __restrict__ segS,
                   int n)
{
    int idx = blockIdx.x * blockDim.x + threadIdx.x;
    if (idx >= n) return;
    int i = idx >> 3, j = idx & 7;
    int seg = segids[i];
    float m = f32_unorder(segM[(size_t)seg * NHC + j]);
    float e = expf(s[idx] - m);
    s[idx] = e;
    atomicAdd(segS + (size_t)seg * NHC + j, e);
}

// ---------------------------------------------------------------------------
// acc[dids[i], h, :] += V[vids[i], h, :] * ex[i, h]   (atomic scatter)
// One 64-lane wave per nnz.
// ---------------------------------------------------------------------------
__global__ __launch_bounds__(64)
void scatter_kernel(const float* __restrict__ Vm, const int* __restrict__ vids,
                    const int* __restrict__ dids, const float* __restrict__ ex,
                    float* acc)
{
    int i = blockIdx.x;
    int lane = threadIdx.x;
    const float* vp = Vm + (size_t)vids[i] * OCC;
    float* ap = acc + (size_t)dids[i] * OCC;
    const float* exr = ex + (size_t)i * NHC;
#pragma unroll
    for (int j = 0; j < NHC; j++)
        atomicAdd(ap + j * 64 + lane, vp[j * 64 + lane] * exr[j]);
}

// ---------------------------------------------------------------------------
// out = acc / segsum (segment-constant denominator); 0 for empty segments.
// ---------------------------------------------------------------------------
__global__ __launch_bounds__(256)
void norm_seg_kernel(float* __restrict__ acc, const float* __restrict__ segS,
                     int n)
{
    int idx = blockIdx.x * blockDim.x + threadIdx.x;
    if (idx >= n) return;
    int r = idx >> 9;          // /OC
    int c = idx & 511;
    float s = segS[(size_t)r * NHC + (c >> 6)];
    acc[idx] = (s > 0.f) ? acc[idx] / s : 0.f;
}

// ---------------------------------------------------------------------------
// BatchNorm stats: per-column sum and sumsq over rows (atomic partials).
// blockDim=256; each thread covers cols t and t+256.
// ---------------------------------------------------------------------------
__global__ __launch_bounds__(256)
void bn_stats_kernel(const float* __restrict__ x, float* sums, float* sumsq,
                     int rows)
{
    int t = threadIdx.x;
    float s0 = 0.f, s1 = 0.f, q0 = 0.f, q1 = 0.f;
    for (int r = blockIdx.x; r < rows; r += gridDim.x) {
        const float* xp = x + (size_t)r * OCC;
        float a = xp[t], b = xp[t + 256];
        s0 += a; q0 += a * a;
        s1 += b; q1 += b * b;
    }
    atomicAdd(&sums[t], s0);
    atomicAdd(&sums[t + 256], s1);
    atomicAdd(&sumsq[t], q0);
    atomicAdd(&sumsq[t + 256], q1);
}

__global__ __launch_bounds__(256)
void bn_apply_kernel(const float* __restrict__ x, const float* __restrict__ sums,
                     const float* __restrict__ sumsq, const float* __restrict__ g,
                     const float* __restrict__ b, float* __restrict__ y,
                     int rows)
{
    int idx = blockIdx.x * blockDim.x + threadIdx.x;
    if (idx >= rows * OCC) return;
    int c = idx & 511;
    float inv_n = 1.f / (float)rows;
    float mu = sums[c] * inv_n;
    float var = sumsq[c] * inv_n - mu * mu;
    float rstd = rsqrtf(var + EPSBN);
    y[idx] = (x[idx] - mu) * rstd * g[c] + b[c];
}

// ---------------------------------------------------------------------------

static inline void launch_gemm(const float* A, const float* B, float* C,
                               int M, int N, int K, const float* bias,
                               const float* res, int act, hipStream_t stream)
{
    dim3 b(32, 32);
    dim3 g(N / 32, (M + 31) / 32);
    hipLaunchKernelGGL(gemm_kernel, g, b, 0, stream, A, B, C, M, N, K, bias, res, act);
}

extern "C" void kernel_launch(void* const* d_in, const int* in_sizes, int n_in,
                              void* d_out, int out_size, void* d_ws, size_t ws_size,
                              hipStream_t stream)
{
    const float* q         = (const float*)d_in[0];
    const float* k         = (const float*)d_in[1];
    /* v = d_in[2] is unused by the reference */
    const float* edge_feat = (const float*)d_in[3];
    const float* Wq_n2h    = (const float*)d_in[4];
    const float* Wk_n2h    = (const float*)d_in[5];
    const float* Wv_n2h    = (const float*)d_in[6];
    const float* Wo_n2h    = (const float*)d_in[7];
    const float* We        = (const float*)d_in[8];
    const float* Wq_h2n    = (const float*)d_in[9];
    const float* Wk_h2n    = (const float*)d_in[10];
    const float* Wv_h2n    = (const float*)d_in[11];
    const float* Wo_h2n    = (const float*)d_in[12];
    const float* W1        = (const float*)d_in[13];
    const float* b1        = (const float*)d_in[14];
    const float* W2        = (const float*)d_in[15];
    const float* b2        = (const float*)d_in[16];
    const float* Wres      = (const float*)d_in[17];
    const float* g1        = (const float*)d_in[18];
    const float* beta1     = (const float*)d_in[19];
    const float* g2        = (const float*)d_in[20];
    const float* beta2     = (const float*)d_in[21];
    const int*   node_ids      = (const int*)d_in[22];
    const int*   hyperedge_ids = (const int*)d_in[23];
    float* out = (float*)d_out;
    (void)in_sizes; (void)n_in; (void)out_size;

    // ---- workspace layout (floats), sized against actual ws_size ----
    // d_out doubles as the Q1/Q2/x scratch buffer (lifetimes don't overlap
    // the final BN2 write, and the harness re-poisons it every call anyway).
    float* ws = (float*)d_ws;
    size_t off = 0;
    auto alloc = [&](size_t n) { float* p = ws + off; off += n; return p; };
    float*    bufB   = alloc((size_t)N_NODESC * OCC);     // V1 / nuAcc / y   (25.6M)
    float*    bufE1  = alloc((size_t)N_EDGESC * OCC);     // K1, later K2     (2.56M)
    float*    bufE2  = alloc((size_t)N_EDGESC * OCC);     // heAcc, later V2  (2.56M)
    float*    bufE3  = alloc((size_t)N_EDGESC * OCC);     // he               (2.56M)
    float*    edge_in= alloc((size_t)N_EDGESC * IN_DIMC); // [E,256]          (1.28M)
    float*    sEx    = alloc((size_t)NNZC * NHC);         // scores -> ex     (2M)
    unsigned* segM   = (unsigned*)alloc((size_t)N_NODESC * NHC);  // (0.4M)
    float*    segS   = alloc((size_t)N_NODESC * NHC);             // (0.4M)
    float*    bnstat = alloc(4 * OCC);                    // sums1,sq1,sums2,sq2

    // FFN hidden chunk: use whatever workspace remains.
    size_t ws_floats = ws_size / sizeof(float);
    size_t remain = (ws_floats > off) ? (ws_floats - off) : 0;
    int chunk = (int)((remain / (4 * OCC)) > (size_t)N_NODESC ? (size_t)N_NODESC
                                                              : remain / (4 * OCC));
    if (chunk > 12800) chunk = 12800;
    if (chunk < 128)   chunk = 128;   // degenerate; still bounded by remain check below
    float* ffnh = alloc((size_t)chunk * 4 * OCC);

    float* Qbuf = out;  // Q1 / Q2 / x share d_out
    float* sums1 = bnstat, *sq1 = bnstat + OCC, *sums2 = bnstat + 2 * OCC, *sq2 = bnstat + 3 * OCC;

    // ---- zero the accumulators used by pass 1 ----
    hipMemsetAsync(segM, 0, (size_t)N_NODESC * NHC * 4, stream);
    hipMemsetAsync(segS, 0, (size_t)N_NODESC * NHC * 4, stream);
    hipMemsetAsync(bufE2, 0, (size_t)N_EDGESC * OCC * 4, stream);   // heAcc
    hipMemsetAsync(bnstat, 0, 4 * OCC * 4, stream);

    // ---- node -> hyperedge attention ----
    launch_gemm(edge_feat, We, edge_in, N_EDGESC, IN_DIMC, IN_DIMC, nullptr, nullptr, 0, stream);
    launch_gemm(k, Wq_n2h, Qbuf, N_NODESC, OCC, IN_DIMC, nullptr, nullptr, 0, stream);    // Q1
    launch_gemm(edge_in, Wk_n2h, bufE1, N_EDGESC, OCC, IN_DIMC, nullptr, nullptr, 0, stream); // K1
    launch_gemm(k, Wv_n2h, bufB, N_NODESC, OCC, IN_DIMC, nullptr, nullptr, 0, stream);    // V1

    hipLaunchKernelGGL(score_kernel, dim3(NNZC), dim3(64), 0, stream,
                       Qbuf, node_ids, bufE1, hyperedge_ids, hyperedge_ids, sEx, segM);
    hipLaunchKernelGGL(expsum_kernel, dim3((NNZC * NHC + 255) / 256), dim3(256), 0, stream,
                       sEx, hyperedge_ids, segM, segS, NNZC * NHC);
    hipLaunchKernelGGL(scatter_kernel, dim3(NNZC), dim3(64), 0, stream,
                       bufB, node_ids, hyperedge_ids, sEx, bufE2);                        // heAcc
    hipLaunchKernelGGL(norm_seg_kernel, dim3((N_EDGESC * OCC + 255) / 256), dim3(256), 0, stream,
                       bufE2, segS, N_EDGESC * OCC);
    launch_gemm(bufE2, Wo_n2h, bufE3, N_EDGESC, OCC, OCC, nullptr, nullptr, 0, stream);   // he

    // ---- hyperedge -> node attention ----
    launch_gemm(q, Wq_h2n, Qbuf, N_NODESC, OCC, IN_DIMC, nullptr, nullptr, 0, stream);    // Q2
    launch_gemm(bufE3, Wk_h2n, bufE1, N_EDGESC, OCC, OCC, nullptr, nullptr, 0, stream);   // K2
    launch_gemm(bufE3, Wv_h2n, bufE2, N_EDGESC, OCC, OCC, nullptr, nullptr, 0, stream);   // V2

    hipMemsetAsync(segM, 0, (size_t)N_NODESC * NHC * 4, stream);
    hipMemsetAsync(segS, 0, (size_t)N_NODESC * NHC * 4, stream);

    hipLaunchKernelGGL(score_kernel, dim3(NNZC), dim3(64), 0, stream,
                       Qbuf, node_ids, bufE1, hyperedge_ids, node_ids, sEx, segM);

    hipMemsetAsync(bufB, 0, (size_t)N_NODESC * OCC * 4, stream);    // nuAcc (V1 dead)

    hipLaunchKernelGGL(expsum_kernel, dim3((NNZC * NHC + 255) / 256), dim3(256), 0, stream,
                       sEx, node_ids, segM, segS, NNZC * NHC);
    hipLaunchKernelGGL(scatter_kernel, dim3(NNZC), dim3(64), 0, stream,
                       bufE2, hyperedge_ids, node_ids, sEx, bufB);                        // nuAcc
    hipLaunchKernelGGL(norm_seg_kernel, dim3((N_NODESC * OCC + 255) / 256), dim3(256), 0, stream,
                       bufB, segS, N_NODESC * OCC);

    // ---- x = q @ Wres + nu @ Wo_h2n  (x lives in d_out) ----
    launch_gemm(q, Wres, Qbuf, N_NODESC, OCC, IN_DIMC, nullptr, nullptr, 0, stream);
    launch_gemm(bufB, Wo_h2n, Qbuf, N_NODESC, OCC, OCC, nullptr, Qbuf, 0, stream);

    // ---- BN1 (in place on x) ----
    hipLaunchKernelGGL(bn_stats_kernel, dim3(512), dim3(256), 0, stream, Qbuf, sums1, sq1, N_NODESC);
    hipLaunchKernelGGL(bn_apply_kernel, dim3((N_NODESC * OCC + 255) / 256), dim3(256), 0, stream,
                       Qbuf, sums1, sq1, g1, beta1, Qbuf, N_NODESC);

    // ---- FFN, row-chunked; y = x + ffn -> bufB ----
    for (int c0 = 0; c0 < N_NODESC; c0 += chunk) {
        int mrows = (N_NODESC - c0 < chunk) ? (N_NODESC - c0) : chunk;
        const float* xc = Qbuf + (size_t)c0 * OCC;
        float* yc = bufB + (size_t)c0 * OCC;
        launch_gemm(xc, W1, ffnh, mrows, 4 * OCC, OCC, b1, nullptr, 1, stream);   // gelu(x@W1+b1)
        launch_gemm(ffnh, W2, yc, mrows, OCC, 4 * OCC, b2, xc, 0, stream);        // +b2 +x
    }

    // ---- BN2 -> d_out ----
    hipLaunchKernelGGL(bn_stats_kernel, dim3(512), dim3(256), 0, stream, bufB, sums2, sq2, N_NODESC);
    hipLaunchKernelGGL(bn_apply_kernel, dim3((N_NODESC * OCC + 255) / 256), dim3(256), 0, stream,
                       bufB, sums2, sq2, g2, beta2, out, N_NODESC);
}

// Round 4
// 2904.228 us; speedup vs baseline: 6.7390x; 6.7390x over previous
//
#include <hip/hip_runtime.h>
#include <math.h>
#include <stdint.h>

#define N_NODESC 50000
#define N_EDGESC 5000
#define NNZC     250000
#define IN_DIMC  256
#define OCC      512
#define NHC      8
#define EPSBN    1e-5f

typedef __attribute__((ext_vector_type(8))) short short8;   // 8 bf16 (4 VGPRs)
typedef __attribute__((ext_vector_type(4))) float f32x4;    // MFMA C/D
typedef __attribute__((ext_vector_type(4))) unsigned short u16x4;
typedef unsigned short u16;

__device__ __forceinline__ u16 f2b(float f) {
    union { float f; unsigned u; } v; v.f = f;
    unsigned r = v.u + 0x7fffu + ((v.u >> 16) & 1u);   // RNE
    return (u16)(r >> 16);
}

// async global->LDS, 16B per lane; LDS dest = wave-uniform base + lane*16
__device__ __forceinline__ void gload16(const u16* g, u16* l) {
    __builtin_amdgcn_global_load_lds(
        (const __attribute__((address_space(1))) unsigned int*)g,
        (__attribute__((address_space(3))) unsigned int*)l, 16, 0, 0);
}

// ---------------------------------------------------------------------------
// MFMA bf16 GEMM: C[M,N] = A[M,K] @ Bt[N,K]^T  (+bias)(gelu)(+resF) -> outF/outB
// 128x128 tile, BK=64, 4 waves (2x2), 16x16x32 MFMA, fp32 accum.
// LDS tiles [128][64] bf16, chunk swizzle phys = log ^ (row&7); the global
// SOURCE is inverse-swizzled so global_load_lds' linear dest lands swizzled
// (both-sides-or-neither rule), reads apply the same XOR.
// ---------------------------------------------------------------------------
__global__ __launch_bounds__(256)
void gemm_mfma(const u16* __restrict__ A, const u16* __restrict__ Bt,
               int M, int N, int K,
               const float* __restrict__ bias, int act,
               const float* resF, float* outF, u16* outB)
{
    __shared__ u16 As[128 * 64];
    __shared__ u16 Bs[128 * 64];
    const int tid  = threadIdx.x;
    const int wid  = tid >> 6, lane = tid & 63;
    const int wr   = wid >> 1, wc = wid & 1;
    const int m0   = blockIdx.y * 128, n0 = blockIdx.x * 128;

    f32x4 acc[4][4] = {};

    const int srow   = wid * 32 + (lane >> 3);             // +j*8 per instr
    const int schunk = (lane & 7) ^ ((lane >> 3) & 7);     // inverse swizzle at source
    const int nk = K >> 6;

    for (int kt = 0; kt < nk; ++kt) {
        const int kb = kt * 64;
#pragma unroll
        for (int j = 0; j < 4; j++) {                       // stage A (16KB)
            int gr = m0 + srow + j * 8;
            if (gr >= M) gr = M - 1;                        // clamp; rows>=M unused
            gload16(A + (size_t)gr * K + kb + schunk * 8, &As[(wid * 32 + j * 8) * 64]);
        }
#pragma unroll
        for (int j = 0; j < 4; j++) {                       // stage Bt (16KB)
            int r = srow + j * 8;                           // N multiple of 128
            gload16(Bt + (size_t)(n0 + r) * K + kb + schunk * 8, &Bs[(wid * 32 + j * 8) * 64]);
        }
        __syncthreads();                                    // vmcnt(0) auto before barrier
#pragma unroll
        for (int ks = 0; ks < 2; ++ks) {
            short8 af[4], bfr[4];
#pragma unroll
            for (int mi = 0; mi < 4; mi++) {
                int r  = wr * 64 + mi * 16 + (lane & 15);
                int pc = ((lane >> 4) + ks * 4) ^ (r & 7);
                af[mi] = *(const short8*)&As[r * 64 + pc * 8];
            }
#pragma unroll
            for (int ni = 0; ni < 4; ni++) {
                int r  = wc * 64 + ni * 16 + (lane & 15);
                int pc = ((lane >> 4) + ks * 4) ^ (r & 7);
                bfr[ni] = *(const short8*)&Bs[r * 64 + pc * 8];
            }
#pragma unroll
            for (int mi = 0; mi < 4; mi++)
#pragma unroll
                for (int ni = 0; ni < 4; ni++)
                    acc[mi][ni] = __builtin_amdgcn_mfma_f32_16x16x32_bf16(
                        af[mi], bfr[ni], acc[mi][ni], 0, 0, 0);
        }
        __syncthreads();
    }

    // epilogue: C row = m0+wr*64+mi*16+(lane>>4)*4+j ; col = n0+wc*64+ni*16+(lane&15)
#pragma unroll
    for (int mi = 0; mi < 4; mi++) {
#pragma unroll
        for (int j = 0; j < 4; j++) {
            int row = m0 + wr * 64 + mi * 16 + (lane >> 4) * 4 + j;
            if (row >= M) continue;
#pragma unroll
            for (int ni = 0; ni < 4; ni++) {
                int col = n0 + wc * 64 + ni * 16 + (lane & 15);
                float v = acc[mi][ni][j];
                if (bias) v += bias[col];
                if (act)  v = 0.5f * v * (1.f + erff(v * 0.70710678118654752f));
                size_t o = (size_t)row * N + col;
                if (resF) v += resF[o];
                if (outF) outF[o] = v;
                if (outB) outB[o] = f2b(v);
            }
        }
    }
}

// ---------------------------------------------------------------------------
// Weight transpose+cast: Wt[n][k] = bf16(W[k][n]).  K,N multiples of 32.
// ---------------------------------------------------------------------------
__global__ __launch_bounds__(256)
void wcast_kernel(const float* __restrict__ W, u16* __restrict__ Wt, int K, int N)
{
    __shared__ float t[32][33];
    int k0 = blockIdx.y * 32, n0 = blockIdx.x * 32;
    int tx = threadIdx.x & 31, ty = threadIdx.x >> 5;      // 32x8
    for (int i = ty; i < 32; i += 8)
        t[i][tx] = W[(size_t)(k0 + i) * N + n0 + tx];
    __syncthreads();
    for (int i = ty; i < 32; i += 8)
        Wt[(size_t)(n0 + i) * K + k0 + tx] = f2b(t[tx][i]);
}

// elementwise fp32 -> bf16 (n multiple of 4)
__global__ __launch_bounds__(256)
void cast_kernel(const float* __restrict__ in, u16* __restrict__ out, int n)
{
    int i = (blockIdx.x * 256 + threadIdx.x) * 4;
    if (i >= n) return;
    const float4 v = *(const float4*)(in + i);
    u16x4 o; o.x = f2b(v.x); o.y = f2b(v.y); o.z = f2b(v.z); o.w = f2b(v.w);
    *(u16x4*)(out + i) = o;
}

// ---------------------------------------------------------------------------
// Segment-softmax machinery
// ---------------------------------------------------------------------------
__device__ __forceinline__ unsigned f32_order(float f) {
    unsigned u = __float_as_uint(f);
    return (u & 0x80000000u) ? ~u : (u | 0x80000000u);
}
__device__ __forceinline__ float f32_unorder(unsigned u) {
    unsigned b = (u & 0x80000000u) ? (u & 0x7FFFFFFFu) : ~u;
    return __uint_as_float(b);
}

__global__ __launch_bounds__(64)
void score_kernel(const float* __restrict__ Qm, const int* __restrict__ qids,
                  const float* __restrict__ Km, const int* __restrict__ kids,
                  const int* __restrict__ segids,
                  float* __restrict__ sout, unsigned* __restrict__ segM)
{
    int i = blockIdx.x;
    int lane = threadIdx.x;
    const float* qp = Qm + (size_t)qids[i] * OCC;
    const float* kp = Km + (size_t)kids[i] * OCC;
    float prod[NHC];
#pragma unroll
    for (int j = 0; j < NHC; j++)
        prod[j] = qp[j * 64 + lane] * kp[j * 64 + lane];
#pragma unroll
    for (int j = 0; j < NHC; j++) {
        float v = prod[j];
        for (int o = 32; o > 0; o >>= 1) v += __shfl_xor(v, o, 64);
        prod[j] = v;
    }
    if (lane < NHC) {
        float s = 0.f;
#pragma unroll
        for (int j = 0; j < NHC; j++) if (lane == j) s = prod[j];
        s *= 0.125f;
        sout[(size_t)i * NHC + lane] = s;
        atomicMax(segM + (size_t)segids[i] * NHC + lane, f32_order(s));
    }
}

__global__ __launch_bounds__(256)
void expsum_kernel(float* __restrict__ s, const int* __restrict__ segids,
                   const unsigned* __restrict__ segM, float* __restrict__ segS,
                   int n)
{
    int idx = blockIdx.x * blockDim.x + threadIdx.x;
    if (idx >= n) return;
    int i = idx >> 3, j = idx & 7;
    int seg = segids[i];
    float m = f32_unorder(segM[(size_t)seg * NHC + j]);
    float e = expf(s[idx] - m);
    s[idx] = e;
    atomicAdd(segS + (size_t)seg * NHC + j, e);
}

__global__ __launch_bounds__(64)
void scatter_kernel(const float* __restrict__ Vm, const int* __restrict__ vids,
                    const int* __restrict__ dids, const float* __restrict__ ex,
                    float* acc)
{
    int i = blockIdx.x;
    int lane = threadIdx.x;
    const float* vp = Vm + (size_t)vids[i] * OCC;
    float* ap = acc + (size_t)dids[i] * OCC;
    const float* exr = ex + (size_t)i * NHC;
#pragma unroll
    for (int j = 0; j < NHC; j++)
        atomicAdd(ap + j * 64 + lane, vp[j * 64 + lane] * exr[j]);
}

// normalize by segment sum, write bf16 (0 for empty segments)
__global__ __launch_bounds__(256)
void norm_seg_b_kernel(const float* __restrict__ acc, const float* __restrict__ segS,
                       u16* __restrict__ outb, int n)
{
    int idx = blockIdx.x * blockDim.x + threadIdx.x;
    if (idx >= n) return;
    int r = idx >> 9;
    int c = idx & 511;
    float s = segS[(size_t)r * NHC + (c >> 6)];
    outb[idx] = f2b((s > 0.f) ? acc[idx] / s : 0.f);
}

// ---------------------------------------------------------------------------
// BatchNorm
// ---------------------------------------------------------------------------
__global__ __launch_bounds__(256)
void bn_stats_kernel(const float* __restrict__ x, float* sums, float* sumsq,
                     int rows)
{
    int t = threadIdx.x;
    float s0 = 0.f, s1 = 0.f, q0 = 0.f, q1 = 0.f;
    for (int r = blockIdx.x; r < rows; r += gridDim.x) {
        const float* xp = x + (size_t)r * OCC;
        float a = xp[t], b = xp[t + 256];
        s0 += a; q0 += a * a;
        s1 += b; q1 += b * b;
    }
    atomicAdd(&sums[t], s0);
    atomicAdd(&sums[t + 256], s1);
    atomicAdd(&sumsq[t], q0);
    atomicAdd(&sumsq[t + 256], q1);
}

__global__ __launch_bounds__(256)
void bn_apply_kernel(const float* __restrict__ x, const float* __restrict__ sums,
                     const float* __restrict__ sumsq, const float* __restrict__ g,
                     const float* __restrict__ b, float* y, int rows)
{
    int idx = blockIdx.x * blockDim.x + threadIdx.x;
    if (idx >= rows * OCC) return;
    int c = idx & 511;
    float inv_n = 1.f / (float)rows;
    float mu = sums[c] * inv_n;
    float var = sumsq[c] * inv_n - mu * mu;
    float rstd = rsqrtf(var + EPSBN);
    y[idx] = (x[idx] - mu) * rstd * g[c] + b[c];
}

// ---------------------------------------------------------------------------

static inline void launch_mfma(const u16* A, const u16* Bt, int M, int N, int K,
                               const float* bias, int act, const float* resF,
                               float* outF, u16* outB, hipStream_t s)
{
    dim3 g(N / 128, (M + 127) / 128);
    hipLaunchKernelGGL(gemm_mfma, g, dim3(256), 0, s, A, Bt, M, N, K,
                       bias, act, resF, outF, outB);
}
static inline void launch_wcast(const float* W, u16* Wt, int K, int N, hipStream_t s)
{
    hipLaunchKernelGGL(wcast_kernel, dim3(N / 32, K / 32), dim3(256), 0, s, W, Wt, K, N);
}
static inline void launch_cast(const float* in, u16* out, int n, hipStream_t s)
{
    hipLaunchKernelGGL(cast_kernel, dim3((n / 4 + 255) / 256), dim3(256), 0, s, in, out, n);
}

extern "C" void kernel_launch(void* const* d_in, const int* in_sizes, int n_in,
                              void* d_out, int out_size, void* d_ws, size_t ws_size,
                              hipStream_t stream)
{
    const float* q         = (const float*)d_in[0];
    const float* k         = (const float*)d_in[1];
    /* v = d_in[2] unused by the reference */
    const float* edge_feat = (const float*)d_in[3];
    const float* Wq_n2h    = (const float*)d_in[4];
    const float* Wk_n2h    = (const float*)d_in[5];
    const float* Wv_n2h    = (const float*)d_in[6];
    const float* Wo_n2h    = (const float*)d_in[7];
    const float* We        = (const float*)d_in[8];
    const float* Wq_h2n    = (const float*)d_in[9];
    const float* Wk_h2n    = (const float*)d_in[10];
    const float* Wv_h2n    = (const float*)d_in[11];
    const float* Wo_h2n    = (const float*)d_in[12];
    const float* W1        = (const float*)d_in[13];
    const float* b1        = (const float*)d_in[14];
    const float* W2        = (const float*)d_in[15];
    const float* b2        = (const float*)d_in[16];
    const float* Wres      = (const float*)d_in[17];
    const float* g1        = (const float*)d_in[18];
    const float* beta1     = (const float*)d_in[19];
    const float* g2        = (const float*)d_in[20];
    const float* beta2     = (const float*)d_in[21];
    const int*   node_ids      = (const int*)d_in[22];
    const int*   hyperedge_ids = (const int*)d_in[23];
    float* out = (float*)d_out;
    (void)in_sizes; (void)n_in; (void)out_size;

    // ---- workspace layout (float-equivalents, 16B-aligned) ----
    float* ws = (float*)d_ws;
    size_t off = 0;
    auto allocF = [&](size_t n) { off = (off + 3) & ~(size_t)3; float* p = ws + off; off += n; return p; };
    auto allocB = [&](size_t nelem) { return (u16*)allocF((nelem + 1) / 2); };

    float* bufB  = allocF((size_t)N_NODESC * OCC);   // V1 fp32 / nuAcc / y
    float* bufE1 = allocF((size_t)N_EDGESC * OCC);   // K1 / K2 fp32
    float* bufE2 = allocF((size_t)N_EDGESC * OCC);   // heAcc / V2 fp32
    u16*   heAB  = allocB((size_t)N_EDGESC * OCC);   // normalized heAcc bf16
    u16*   heB   = allocB((size_t)N_EDGESC * OCC);   // he bf16
    u16*   eiB   = allocB((size_t)N_EDGESC * IN_DIMC); // edge_in bf16
    float* sEx   = allocF((size_t)NNZC * NHC);
    unsigned* segM = (unsigned*)allocF((size_t)N_NODESC * NHC);
    float* segS  = allocF((size_t)N_NODESC * NHC);
    float* bnstat= allocF(4 * OCC);
    u16*   kB    = allocB((size_t)N_NODESC * IN_DIMC); // k bf16   } contiguous:
    u16*   qB    = allocB((size_t)N_NODESC * IN_DIMC); // q bf16   } nuB overlays both
    u16*   nuB   = kB;                                  // 50000*512 bf16 overlay

    // weight bf16 transposed [N][K]
    u16* WeT  = allocB(256 * 256);
    u16* WqnT = allocB(512 * 256);
    u16* WknT = allocB(512 * 256);
    u16* WvnT = allocB(512 * 256);
    u16* WonT = allocB(512 * 512);
    u16* WqhT = allocB(512 * 256);
    u16* WkhT = allocB(512 * 512);
    u16* WvhT = allocB(512 * 512);
    u16* WohT = allocB(512 * 512);
    u16* W1T  = allocB(2048 * 512);
    u16* W2T  = allocB(512 * 2048);
    u16* WrT  = allocB(512 * 256);

    // FFN chunk sized to remaining workspace
    size_t ws_floats = ws_size / sizeof(float);
    size_t remain = (ws_floats > off + 8) ? (ws_floats - off - 8) : 0;
    long ch = (long)(remain / 1280);        // per row: 1024 (ffnh bf16) + 256 (x bf16)
    if (ch > 12800) ch = 12800;
    if (ch < 1024)  ch = 1024;
    int CH = (int)ch;
    u16* xbC  = allocB((size_t)CH * OCC);
    u16* ffnB = allocB((size_t)CH * 4 * OCC);

    float* Qbuf = out;  // Q1 / Q2 / xres / x live in d_out
    float* sums1 = bnstat, *sq1 = bnstat + OCC, *sums2 = bnstat + 2 * OCC, *sq2 = bnstat + 3 * OCC;

    // ---- weight casts + activation casts ----
    launch_wcast(We,     WeT,  256, 256, stream);
    launch_wcast(Wq_n2h, WqnT, 256, 512, stream);
    launch_wcast(Wk_n2h, WknT, 256, 512, stream);
    launch_wcast(Wv_n2h, WvnT, 256, 512, stream);
    launch_wcast(Wo_n2h, WonT, 512, 512, stream);
    launch_wcast(Wq_h2n, WqhT, 256, 512, stream);
    launch_wcast(Wk_h2n, WkhT, 512, 512, stream);
    launch_wcast(Wv_h2n, WvhT, 512, 512, stream);
    launch_wcast(Wo_h2n, WohT, 512, 512, stream);
    launch_wcast(W1,     W1T,  512, 2048, stream);
    launch_wcast(W2,     W2T,  2048, 512, stream);
    launch_wcast(Wres,   WrT,  256, 512, stream);
    launch_cast(k, kB, N_NODESC * IN_DIMC, stream);
    launch_cast(q, qB, N_NODESC * IN_DIMC, stream);

    // edge_feat bf16 scratch: xbC has CH*512 >= 5000*256 elems (CH >= 2500 always)
    u16* efB = (CH * OCC >= N_EDGESC * IN_DIMC) ? xbC : heB;
    launch_cast(edge_feat, efB, N_EDGESC * IN_DIMC, stream);

    // ---- zero accumulators ----
    hipMemsetAsync(segM, 0, (size_t)N_NODESC * NHC * 4, stream);
    hipMemsetAsync(segS, 0, (size_t)N_NODESC * NHC * 4, stream);
    hipMemsetAsync(bufE2, 0, (size_t)N_EDGESC * OCC * 4, stream);   // heAcc
    hipMemsetAsync(bnstat, 0, 4 * OCC * 4, stream);

    // ---- node -> hyperedge ----
    launch_mfma(efB, WeT, N_EDGESC, IN_DIMC, IN_DIMC, nullptr, 0, nullptr, nullptr, eiB, stream); // edge_in
    launch_mfma(kB, WqnT, N_NODESC, OCC, IN_DIMC, nullptr, 0, nullptr, Qbuf, nullptr, stream);    // Q1
    launch_mfma(eiB, WknT, N_EDGESC, OCC, IN_DIMC, nullptr, 0, nullptr, bufE1, nullptr, stream);  // K1
    launch_mfma(kB, WvnT, N_NODESC, OCC, IN_DIMC, nullptr, 0, nullptr, bufB, nullptr, stream);    // V1

    hipLaunchKernelGGL(score_kernel, dim3(NNZC), dim3(64), 0, stream,
                       Qbuf, node_ids, bufE1, hyperedge_ids, hyperedge_ids, sEx, segM);
    hipLaunchKernelGGL(expsum_kernel, dim3((NNZC * NHC + 255) / 256), dim3(256), 0, stream,
                       sEx, hyperedge_ids, segM, segS, NNZC * NHC);
    hipLaunchKernelGGL(scatter_kernel, dim3(NNZC), dim3(64), 0, stream,
                       bufB, node_ids, hyperedge_ids, sEx, bufE2);
    hipLaunchKernelGGL(norm_seg_b_kernel, dim3((N_EDGESC * OCC + 255) / 256), dim3(256), 0, stream,
                       bufE2, segS, heAB, N_EDGESC * OCC);
    launch_mfma(heAB, WonT, N_EDGESC, OCC, OCC, nullptr, 0, nullptr, nullptr, heB, stream);       // he

    // ---- hyperedge -> node ----
    launch_mfma(qB, WqhT, N_NODESC, OCC, IN_DIMC, nullptr, 0, nullptr, Qbuf, nullptr, stream);    // Q2
    launch_mfma(heB, WkhT, N_EDGESC, OCC, OCC, nullptr, 0, nullptr, bufE1, nullptr, stream);      // K2
    launch_mfma(heB, WvhT, N_EDGESC, OCC, OCC, nullptr, 0, nullptr, bufE2, nullptr, stream);      // V2

    hipMemsetAsync(segM, 0, (size_t)N_NODESC * NHC * 4, stream);
    hipMemsetAsync(segS, 0, (size_t)N_NODESC * NHC * 4, stream);

    hipLaunchKernelGGL(score_kernel, dim3(NNZC), dim3(64), 0, stream,
                       Qbuf, node_ids, bufE1, hyperedge_ids, node_ids, sEx, segM);

    // xres = q @ Wres -> d_out (safe: score2 above already consumed Q2 from d_out)
    launch_mfma(qB, WrT, N_NODESC, OCC, IN_DIMC, nullptr, 0, nullptr, Qbuf, nullptr, stream);

    hipMemsetAsync(bufB, 0, (size_t)N_NODESC * OCC * 4, stream);   // nuAcc (V1 dead)

    hipLaunchKernelGGL(expsum_kernel, dim3((NNZC * NHC + 255) / 256), dim3(256), 0, stream,
                       sEx, node_ids, segM, segS, NNZC * NHC);
    hipLaunchKernelGGL(scatter_kernel, dim3(NNZC), dim3(64), 0, stream,
                       bufE2, hyperedge_ids, node_ids, sEx, bufB);
    hipLaunchKernelGGL(norm_seg_b_kernel, dim3((N_NODESC * OCC + 255) / 256), dim3(256), 0, stream,
                       bufB, segS, nuB, N_NODESC * OCC);           // nu bf16 (overlays kB/qB)

    // ---- x = nu @ Wo_h2n + xres  -> d_out fp32 ----
    launch_mfma(nuB, WohT, N_NODESC, OCC, OCC, nullptr, 0, Qbuf, Qbuf, nullptr, stream);

    // ---- BN1 in place on x (d_out) ----
    hipLaunchKernelGGL(bn_stats_kernel, dim3(512), dim3(256), 0, stream, Qbuf, sums1, sq1, N_NODESC);
    hipLaunchKernelGGL(bn_apply_kernel, dim3((N_NODESC * OCC + 255) / 256), dim3(256), 0, stream,
                       Qbuf, sums1, sq1, g1, beta1, Qbuf, N_NODESC);

    // ---- FFN in chunks: y = x + gelu(x@W1+b1)@W2+b2 -> bufB ----
    for (int c0 = 0; c0 < N_NODESC; c0 += CH) {
        int mrows = (N_NODESC - c0 < CH) ? (N_NODESC - c0) : CH;
        const float* xc = Qbuf + (size_t)c0 * OCC;
        launch_cast(xc, xbC, mrows * OCC, stream);
        launch_mfma(xbC, W1T, mrows, 4 * OCC, OCC, b1, 1, nullptr, nullptr, ffnB, stream);
        launch_mfma(ffnB, W2T, mrows, OCC, 4 * OCC, b2, 0, xc, bufB + (size_t)c0 * OCC, nullptr, stream);
    }

    // ---- BN2 -> d_out ----
    hipLaunchKernelGGL(bn_stats_kernel, dim3(512), dim3(256), 0, stream, bufB, sums2, sq2, N_NODESC);
    hipLaunchKernelGGL(bn_apply_kernel, dim3((N_NODESC * OCC + 255) / 256), dim3(256), 0, stream,
                       bufB, sums2, sq2, g2, beta2, out, N_NODESC);
}

// Round 6
// 2411.054 us; speedup vs baseline: 8.1175x; 1.2045x over previous
//
#include <hip/hip_runtime.h>
#include <math.h>
#include <stdint.h>

#define N_NODESC 50000
#define N_EDGESC 5000
#define NNZC     250000
#define IN_DIMC  256
#define OCC      512
#define NHC      8
#define EPSBN    1e-5f

typedef __attribute__((ext_vector_type(8))) short short8;   // 8 bf16 (4 VGPRs)
typedef __attribute__((ext_vector_type(4))) float f32x4;    // MFMA C/D
typedef __attribute__((ext_vector_type(4))) unsigned short u16x4;
typedef unsigned short u16;

__device__ __forceinline__ u16 f2b(float f) {
    union { float f; unsigned u; } v; v.f = f;
    unsigned r = v.u + 0x7fffu + ((v.u >> 16) & 1u);   // RNE
    return (u16)(r >> 16);
}

// async global->LDS, 16B per lane; LDS dest = wave-uniform base + lane*16
__device__ __forceinline__ void gload16(const u16* g, u16* l) {
    __builtin_amdgcn_global_load_lds(
        (const __attribute__((address_space(1))) unsigned int*)g,
        (__attribute__((address_space(3))) unsigned int*)l, 16, 0, 0);
}

// ---------------------------------------------------------------------------
// MFMA bf16 GEMM: C[M,N] = A[M,K] @ Bt[N,K]^T  (+bias)(gelu)(+resF) -> outF/outB
// 128x128 tile, BK=64, 4 waves (2x2), 16x16x32 MFMA, fp32 accum.
// ---------------------------------------------------------------------------
__global__ __launch_bounds__(256)
void gemm_mfma(const u16* __restrict__ A, const u16* __restrict__ Bt,
               int M, int N, int K,
               const float* __restrict__ bias, int act,
               const float* resF, float* outF, u16* outB)
{
    __shared__ u16 As[128 * 64];
    __shared__ u16 Bs[128 * 64];
    const int tid  = threadIdx.x;
    const int wid  = tid >> 6, lane = tid & 63;
    const int wr   = wid >> 1, wc = wid & 1;
    const int m0   = blockIdx.y * 128, n0 = blockIdx.x * 128;

    f32x4 acc[4][4] = {};

    const int srow   = wid * 32 + (lane >> 3);             // +j*8 per instr
    const int schunk = (lane & 7) ^ ((lane >> 3) & 7);     // inverse swizzle at source
    const int nk = K >> 6;

    for (int kt = 0; kt < nk; ++kt) {
        const int kb = kt * 64;
#pragma unroll
        for (int j = 0; j < 4; j++) {                       // stage A (16KB)
            int gr = m0 + srow + j * 8;
            if (gr >= M) gr = M - 1;                        // clamp; rows>=M unused
            gload16(A + (size_t)gr * K + kb + schunk * 8, &As[(wid * 32 + j * 8) * 64]);
        }
#pragma unroll
        for (int j = 0; j < 4; j++) {                       // stage Bt (16KB)
            int r = srow + j * 8;                           // N multiple of 128
            gload16(Bt + (size_t)(n0 + r) * K + kb + schunk * 8, &Bs[(wid * 32 + j * 8) * 64]);
        }
        __syncthreads();
#pragma unroll
        for (int ks = 0; ks < 2; ++ks) {
            short8 af[4], bfr[4];
#pragma unroll
            for (int mi = 0; mi < 4; mi++) {
                int r  = wr * 64 + mi * 16 + (lane & 15);
                int pc = ((lane >> 4) + ks * 4) ^ (r & 7);
                af[mi] = *(const short8*)&As[r * 64 + pc * 8];
            }
#pragma unroll
            for (int ni = 0; ni < 4; ni++) {
                int r  = wc * 64 + ni * 16 + (lane & 15);
                int pc = ((lane >> 4) + ks * 4) ^ (r & 7);
                bfr[ni] = *(const short8*)&Bs[r * 64 + pc * 8];
            }
#pragma unroll
            for (int mi = 0; mi < 4; mi++)
#pragma unroll
                for (int ni = 0; ni < 4; ni++)
                    acc[mi][ni] = __builtin_amdgcn_mfma_f32_16x16x32_bf16(
                        af[mi], bfr[ni], acc[mi][ni], 0, 0, 0);
        }
        __syncthreads();
    }

#pragma unroll
    for (int mi = 0; mi < 4; mi++) {
#pragma unroll
        for (int j = 0; j < 4; j++) {
            int row = m0 + wr * 64 + mi * 16 + (lane >> 4) * 4 + j;
            if (row >= M) continue;
#pragma unroll
            for (int ni = 0; ni < 4; ni++) {
                int col = n0 + wc * 64 + ni * 16 + (lane & 15);
                float v = acc[mi][ni][j];
                if (bias) v += bias[col];
                if (act)  v = 0.5f * v * (1.f + erff(v * 0.70710678118654752f));
                size_t o = (size_t)row * N + col;
                if (resF) v += resF[o];
                if (outF) outF[o] = v;
                if (outB) outB[o] = f2b(v);
            }
        }
    }
}

// ---------------------------------------------------------------------------
// Weight transpose+cast: Wt[n][k] = bf16(W[k][n]).
// ---------------------------------------------------------------------------
__global__ __launch_bounds__(256)
void wcast_kernel(const float* __restrict__ W, u16* __restrict__ Wt, int K, int N)
{
    __shared__ float t[32][33];
    int k0 = blockIdx.y * 32, n0 = blockIdx.x * 32;
    int tx = threadIdx.x & 31, ty = threadIdx.x >> 5;      // 32x8
    for (int i = ty; i < 32; i += 8)
        t[i][tx] = W[(size_t)(k0 + i) * N + n0 + tx];
    __syncthreads();
    for (int i = ty; i < 32; i += 8)
        Wt[(size_t)(n0 + i) * K + k0 + tx] = f2b(t[tx][i]);
}

__global__ __launch_bounds__(256)
void cast_kernel(const float* __restrict__ in, u16* __restrict__ out, int n)
{
    int i = (blockIdx.x * 256 + threadIdx.x) * 4;
    if (i >= n) return;
    const float4 v = *(const float4*)(in + i);
    u16x4 o; o.x = f2b(v.x); o.y = f2b(v.y); o.z = f2b(v.z); o.w = f2b(v.w);
    *(u16x4*)(out + i) = o;
}

// ---------------------------------------------------------------------------
// CSR build: histogram -> exclusive scan -> fill (perm = nnz sorted by segment)
// ---------------------------------------------------------------------------
__global__ __launch_bounds__(256)
void hist_kernel(const int* __restrict__ ids, int n, int* counts)
{
    int i = blockIdx.x * 256 + threadIdx.x;
    if (i < n) atomicAdd(&counts[ids[i]], 1);
}

__global__ __launch_bounds__(1024)
void scan_kernel(const int* __restrict__ counts, int* __restrict__ offs, int n)
{
    __shared__ int tmp[1024];
    __shared__ int carry;
    int tid = threadIdx.x;
    if (tid == 0) carry = 0;
    __syncthreads();
    for (int base = 0; base < n; base += 1024) {
        int v = (base + tid < n) ? counts[base + tid] : 0;
        tmp[tid] = v;
        __syncthreads();
        for (int o = 1; o < 1024; o <<= 1) {
            int t = (tid >= o) ? tmp[tid - o] : 0;
            __syncthreads();
            tmp[tid] += t;
            __syncthreads();
        }
        if (base + tid < n) offs[base + tid] = carry + tmp[tid] - v;  // exclusive
        __syncthreads();
        if (tid == 0) carry += tmp[1023];
        __syncthreads();
    }
    if (tid == 0) offs[n] = carry;
}

__global__ __launch_bounds__(256)
void fill_kernel(const int* __restrict__ ids, int n, const int* __restrict__ offs,
                 int* cursor, int* __restrict__ perm)
{
    int i = blockIdx.x * 256 + threadIdx.x;
    if (i >= n) return;
    int s = ids[i];
    int p = atomicAdd(&cursor[s], 1);
    perm[offs[s] + p] = i;
}

// ---------------------------------------------------------------------------
// Fused segment attention, pass 1 (segments = hyperedges, deg ~50).
// One 256-thread block (4 waves) per segment. F = K1[seg] fixed; per-nnz
// gathers G=Q1[gid], V=V1[gid]. Online softmax per wave, LDS merge, writes
// normalized out bf16 [seg][h*64+d]. No atomics.
// ---------------------------------------------------------------------------
__global__ __launch_bounds__(256)
void seg_attn_block(const float* __restrict__ F, const float* __restrict__ G,
                    const float* __restrict__ V, const int* __restrict__ gid,
                    const int* __restrict__ offs, const int* __restrict__ perm,
                    u16* __restrict__ outB)
{
    __shared__ float sm[4][NHC], sl[4][NHC], sacc[4][NHC][64];
    const int seg = blockIdx.x;
    const int lane = threadIdx.x & 63, wid = threadIdx.x >> 6;
    const int beg = offs[seg], end = offs[seg + 1];

    float f[NHC], m[NHC], l[NHC], acc[NHC];
#pragma unroll
    for (int h = 0; h < NHC; h++) {
        f[h] = F[(size_t)seg * OCC + h * 64 + lane];
        m[h] = -INFINITY; l[h] = 0.f; acc[h] = 0.f;
    }

    for (int i = beg + wid; i < end; i += 4) {
        int id = gid[perm[i]];
        const float* gp = G + (size_t)id * OCC;
        const float* vp = V + (size_t)id * OCC;
        float gv[NHC], vv[NHC], s[NHC];
#pragma unroll
        for (int h = 0; h < NHC; h++) gv[h] = gp[h * 64 + lane];
#pragma unroll
        for (int h = 0; h < NHC; h++) vv[h] = vp[h * 64 + lane];
#pragma unroll
        for (int h = 0; h < NHC; h++) {
            float p = f[h] * gv[h];
#pragma unroll
            for (int o = 32; o > 0; o >>= 1) p += __shfl_xor(p, o, 64);
            s[h] = p * 0.125f;
        }
#pragma unroll
        for (int h = 0; h < NHC; h++) {
            float mn = fmaxf(m[h], s[h]);
            float sc = __expf(m[h] - mn);
            float w  = __expf(s[h] - mn);
            l[h]   = l[h] * sc + w;
            acc[h] = acc[h] * sc + w * vv[h];
            m[h]   = mn;
        }
    }

#pragma unroll
    for (int h = 0; h < NHC; h++) {
        if (lane == h) { sm[wid][h] = m[h]; sl[wid][h] = l[h]; }
        sacc[wid][h][lane] = acc[h];
    }
    __syncthreads();

    for (int e = threadIdx.x; e < OCC; e += 256) {
        int h = e >> 6, ln = e & 63;
        float M = fmaxf(fmaxf(sm[0][h], sm[1][h]), fmaxf(sm[2][h], sm[3][h]));
        float L = 0.f, A = 0.f;
#pragma unroll
        for (int w = 0; w < 4; w++) {
            float sc = __expf(sm[w][h] - M);
            L += sl[w][h] * sc;
            A += sacc[w][h][ln] * sc;
        }
        outB[(size_t)seg * OCC + e] = f2b((L > 0.f) ? A / L : 0.f);
    }
}

// ---------------------------------------------------------------------------
// Fused segment attention, pass 2 (segments = nodes, deg ~5).
// One wave per segment (4 segments/block). F = Q2[seg] fixed; per-nnz gathers
// G=K2[gid], V=V2[gid] (10MB tables, cache-resident). Writes nu bf16.
// ---------------------------------------------------------------------------
__global__ __launch_bounds__(256)
void seg_attn_wave(const float* __restrict__ F, const float* __restrict__ G,
                   const float* __restrict__ V, const int* __restrict__ gid,
                   const int* __restrict__ offs, const int* __restrict__ perm,
                   u16* __restrict__ outB, int nseg)
{
    const int seg = blockIdx.x * 4 + (threadIdx.x >> 6);
    if (seg >= nseg) return;
    const int lane = threadIdx.x & 63;
    const int beg = offs[seg], end = offs[seg + 1];

    float f[NHC], m[NHC], l[NHC], acc[NHC];
#pragma unroll
    for (int h = 0; h < NHC; h++) {
        f[h] = F[(size_t)seg * OCC + h * 64 + lane];
        m[h] = -INFINITY; l[h] = 0.f; acc[h] = 0.f;
    }

    for (int i = beg; i < end; ++i) {
        int id = gid[perm[i]];
        const float* gp = G + (size_t)id * OCC;
        const float* vp = V + (size_t)id * OCC;
        float gv[NHC], vv[NHC], s[NHC];
#pragma unroll
        for (int h = 0; h < NHC; h++) gv[h] = gp[h * 64 + lane];
#pragma unroll
        for (int h = 0; h < NHC; h++) vv[h] = vp[h * 64 + lane];
#pragma unroll
        for (int h = 0; h < NHC; h++) {
            float p = f[h] * gv[h];
#pragma unroll
            for (int o = 32; o > 0; o >>= 1) p += __shfl_xor(p, o, 64);
            s[h] = p * 0.125f;
        }
#pragma unroll
        for (int h = 0; h < NHC; h++) {
            float mn = fmaxf(m[h], s[h]);
            float sc = __expf(m[h] - mn);
            float w  = __expf(s[h] - mn);
            l[h]   = l[h] * sc + w;
            acc[h] = acc[h] * sc + w * vv[h];
            m[h]   = mn;
        }
    }

#pragma unroll
    for (int h = 0; h < NHC; h++)
        outB[(size_t)seg * OCC + h * 64 + lane] = f2b((l[h] > 0.f) ? acc[h] / l[h] : 0.f);
}

// ---------------------------------------------------------------------------
// BatchNorm
// ---------------------------------------------------------------------------
__global__ __launch_bounds__(256)
void bn_stats_kernel(const float* __restrict__ x, float* sums, float* sumsq,
                     int rows)
{
    int t = threadIdx.x;
    float s0 = 0.f, s1 = 0.f, q0 = 0.f, q1 = 0.f;
    for (int r = blockIdx.x; r < rows; r += gridDim.x) {
        const float* xp = x + (size_t)r * OCC;
        float a = xp[t], b = xp[t + 256];
        s0 += a; q0 += a * a;
        s1 += b; q1 += b * b;
    }
    atomicAdd(&sums[t], s0);
    atomicAdd(&sums[t + 256], s1);
    atomicAdd(&sumsq[t], q0);
    atomicAdd(&sumsq[t + 256], q1);
}

__global__ __launch_bounds__(256)
void bn_apply_kernel(const float* __restrict__ x, const float* __restrict__ sums,
                     const float* __restrict__ sumsq, const float* __restrict__ g,
                     const float* __restrict__ b, float* y, int rows)
{
    int idx = blockIdx.x * blockDim.x + threadIdx.x;
    if (idx >= rows * OCC) return;
    int c = idx & 511;
    float inv_n = 1.f / (float)rows;
    float mu = sums[c] * inv_n;
    float var = sumsq[c] * inv_n - mu * mu;
    float rstd = rsqrtf(var + EPSBN);
    y[idx] = (x[idx] - mu) * rstd * g[c] + b[c];
}

// ---------------------------------------------------------------------------

static inline void launch_mfma(const u16* A, const u16* Bt, int M, int N, int K,
                               const float* bias, int act, const float* resF,
                               float* outF, u16* outB, hipStream_t s)
{
    dim3 g(N / 128, (M + 127) / 128);
    hipLaunchKernelGGL(gemm_mfma, g, dim3(256), 0, s, A, Bt, M, N, K,
                       bias, act, resF, outF, outB);
}
static inline void launch_wcast(const float* W, u16* Wt, int K, int N, hipStream_t s)
{
    hipLaunchKernelGGL(wcast_kernel, dim3(N / 32, K / 32), dim3(256), 0, s, W, Wt, K, N);
}
static inline void launch_cast(const float* in, u16* out, int n, hipStream_t s)
{
    hipLaunchKernelGGL(cast_kernel, dim3((n / 4 + 255) / 256), dim3(256), 0, s, in, out, n);
}

extern "C" void kernel_launch(void* const* d_in, const int* in_sizes, int n_in,
                              void* d_out, int out_size, void* d_ws, size_t ws_size,
                              hipStream_t stream)
{
    const float* q         = (const float*)d_in[0];
    const float* k         = (const float*)d_in[1];
    /* v = d_in[2] unused by the reference */
    const float* edge_feat = (const float*)d_in[3];
    const float* Wq_n2h    = (const float*)d_in[4];
    const float* Wk_n2h    = (const float*)d_in[5];
    const float* Wv_n2h    = (const float*)d_in[6];
    const float* Wo_n2h    = (const float*)d_in[7];
    const float* We        = (const float*)d_in[8];
    const float* Wq_h2n    = (const float*)d_in[9];
    const float* Wk_h2n    = (const float*)d_in[10];
    const float* Wv_h2n    = (const float*)d_in[11];
    const float* Wo_h2n    = (const float*)d_in[12];
    const float* W1        = (const float*)d_in[13];
    const float* b1        = (const float*)d_in[14];
    const float* W2        = (const float*)d_in[15];
    const float* b2        = (const float*)d_in[16];
    const float* Wres      = (const float*)d_in[17];
    const float* g1        = (const float*)d_in[18];
    const float* beta1     = (const float*)d_in[19];
    const float* g2        = (const float*)d_in[20];
    const float* beta2     = (const float*)d_in[21];
    const int*   node_ids      = (const int*)d_in[22];
    const int*   hyperedge_ids = (const int*)d_in[23];
    float* out = (float*)d_out;
    (void)in_sizes; (void)n_in; (void)out_size;

    // ---- workspace layout ----
    float* ws = (float*)d_ws;
    size_t off = 0;
    auto allocF = [&](size_t n) { off = (off + 3) & ~(size_t)3; float* p = ws + off; off += n; return p; };
    auto allocB = [&](size_t nelem) { return (u16*)allocF((nelem + 1) / 2); };
    auto allocI = [&](size_t n) { return (int*)allocF(n); };

    float* bufB  = allocF((size_t)N_NODESC * OCC);   // V1 fp32 / xres / y
    float* bufE1 = allocF((size_t)N_EDGESC * OCC);   // K1 / K2 fp32
    float* bufE2 = allocF((size_t)N_EDGESC * OCC);   // V2 fp32
    u16*   heAB  = allocB((size_t)N_EDGESC * OCC);   // he (pre-Wo) bf16
    u16*   heB   = allocB((size_t)N_EDGESC * OCC);   // he bf16
    u16*   eiB   = allocB((size_t)N_EDGESC * IN_DIMC); // edge_in bf16
    float* bnstat= allocF(4 * OCC);
    u16*   kB    = allocB((size_t)N_NODESC * IN_DIMC); // k bf16   } contiguous:
    u16*   qB    = allocB((size_t)N_NODESC * IN_DIMC); // q bf16   } nuB overlays both
    u16*   nuB   = kB;                                  // 50000*512 bf16 overlay

    // CSR arrays (rebuilt every call; ids are constant inputs)
    int* cnt1  = allocI(N_EDGESC);
    int* cur1  = allocI(N_EDGESC);
    int* offs1 = allocI(N_EDGESC + 4);
    int* perm1 = allocI(NNZC);
    int* cnt2  = allocI(N_NODESC);
    int* cur2  = allocI(N_NODESC);
    int* offs2 = allocI(N_NODESC + 4);
    int* perm2 = allocI(NNZC);

    // weight bf16 transposed [N][K]
    u16* WeT  = allocB(256 * 256);
    u16* WqnT = allocB(512 * 256);
    u16* WknT = allocB(512 * 256);
    u16* WvnT = allocB(512 * 256);
    u16* WonT = allocB(512 * 512);
    u16* WqhT = allocB(512 * 256);
    u16* WkhT = allocB(512 * 512);
    u16* WvhT = allocB(512 * 512);
    u16* WohT = allocB(512 * 512);
    u16* W1T  = allocB(2048 * 512);
    u16* W2T  = allocB(512 * 2048);
    u16* WrT  = allocB(512 * 256);

    // FFN chunk sized to remaining workspace
    size_t ws_floats = ws_size / sizeof(float);
    size_t remain = (ws_floats > off + 8) ? (ws_floats - off - 8) : 0;
    long ch = (long)(remain / 1280);        // per row: 1024 (ffnh bf16) + 256 (x bf16)
    if (ch > 12800) ch = 12800;
    if (ch < 1024)  ch = 1024;
    int CH = (int)ch;
    u16* xbC  = allocB((size_t)CH * OCC);
    u16* ffnB = allocB((size_t)CH * 4 * OCC);

    float* Qbuf = out;  // Q1 / Q2 / x live in d_out
    float* sums1 = bnstat, *sq1 = bnstat + OCC, *sums2 = bnstat + 2 * OCC, *sq2 = bnstat + 3 * OCC;

    // ---- weight + activation casts ----
    launch_wcast(We,     WeT,  256, 256, stream);
    launch_wcast(Wq_n2h, WqnT, 256, 512, stream);
    launch_wcast(Wk_n2h, WknT, 256, 512, stream);
    launch_wcast(Wv_n2h, WvnT, 256, 512, stream);
    launch_wcast(Wo_n2h, WonT, 512, 512, stream);
    launch_wcast(Wq_h2n, WqhT, 256, 512, stream);
    launch_wcast(Wk_h2n, WkhT, 512, 512, stream);
    launch_wcast(Wv_h2n, WvhT, 512, 512, stream);
    launch_wcast(Wo_h2n, WohT, 512, 512, stream);
    launch_wcast(W1,     W1T,  512, 2048, stream);
    launch_wcast(W2,     W2T,  2048, 512, stream);
    launch_wcast(Wres,   WrT,  256, 512, stream);
    launch_cast(k, kB, N_NODESC * IN_DIMC, stream);
    launch_cast(q, qB, N_NODESC * IN_DIMC, stream);
    u16* efB = (CH * OCC >= N_EDGESC * IN_DIMC) ? xbC : heB;  // CH >= 2500 always
    launch_cast(edge_feat, efB, N_EDGESC * IN_DIMC, stream);

    // ---- CSR build (both passes) ----
    hipMemsetAsync(cnt1, 0, N_EDGESC * 4, stream);
    hipMemsetAsync(cur1, 0, N_EDGESC * 4, stream);
    hipMemsetAsync(cnt2, 0, N_NODESC * 4, stream);
    hipMemsetAsync(cur2, 0, N_NODESC * 4, stream);
    hipMemsetAsync(bnstat, 0, 4 * OCC * 4, stream);

    hipLaunchKernelGGL(hist_kernel, dim3((NNZC + 255) / 256), dim3(256), 0, stream,
                       hyperedge_ids, NNZC, cnt1);
    hipLaunchKernelGGL(scan_kernel, dim3(1), dim3(1024), 0, stream, cnt1, offs1, N_EDGESC);
    hipLaunchKernelGGL(fill_kernel, dim3((NNZC + 255) / 256), dim3(256), 0, stream,
                       hyperedge_ids, NNZC, offs1, cur1, perm1);
    hipLaunchKernelGGL(hist_kernel, dim3((NNZC + 255) / 256), dim3(256), 0, stream,
                       node_ids, NNZC, cnt2);
    hipLaunchKernelGGL(scan_kernel, dim3(1), dim3(1024), 0, stream, cnt2, offs2, N_NODESC);
    hipLaunchKernelGGL(fill_kernel, dim3((NNZC + 255) / 256), dim3(256), 0, stream,
                       node_ids, NNZC, offs2, cur2, perm2);

    // ---- node -> hyperedge ----
    launch_mfma(efB, WeT, N_EDGESC, IN_DIMC, IN_DIMC, nullptr, 0, nullptr, nullptr, eiB, stream); // edge_in
    launch_mfma(kB, WqnT, N_NODESC, OCC, IN_DIMC, nullptr, 0, nullptr, Qbuf, nullptr, stream);    // Q1
    launch_mfma(eiB, WknT, N_EDGESC, OCC, IN_DIMC, nullptr, 0, nullptr, bufE1, nullptr, stream);  // K1
    launch_mfma(kB, WvnT, N_NODESC, OCC, IN_DIMC, nullptr, 0, nullptr, bufB, nullptr, stream);    // V1

    // fused: he_pre = softmax-weighted segment sum, normalized, bf16
    hipLaunchKernelGGL(seg_attn_block, dim3(N_EDGESC), dim3(256), 0, stream,
                       bufE1 /*K1*/, Qbuf /*Q1*/, bufB /*V1*/, node_ids, offs1, perm1, heAB);
    launch_mfma(heAB, WonT, N_EDGESC, OCC, OCC, nullptr, 0, nullptr, nullptr, heB, stream);       // he

    // ---- hyperedge -> node ----
    launch_mfma(qB, WqhT, N_NODESC, OCC, IN_DIMC, nullptr, 0, nullptr, Qbuf, nullptr, stream);    // Q2
    launch_mfma(heB, WkhT, N_EDGESC, OCC, OCC, nullptr, 0, nullptr, bufE1, nullptr, stream);      // K2
    launch_mfma(heB, WvhT, N_EDGESC, OCC, OCC, nullptr, 0, nullptr, bufE2, nullptr, stream);      // V2
    launch_mfma(qB, WrT, N_NODESC, OCC, IN_DIMC, nullptr, 0, nullptr, bufB, nullptr, stream);     // xres (bufB free)

    // fused: nu bf16 -> nuB (overlays kB/qB; both dead now)
    hipLaunchKernelGGL(seg_attn_wave, dim3((N_NODESC + 3) / 4), dim3(256), 0, stream,
                       Qbuf /*Q2*/, bufE1 /*K2*/, bufE2 /*V2*/, hyperedge_ids, offs2, perm2,
                       nuB, N_NODESC);

    // ---- x = nu @ Wo_h2n + xres -> d_out fp32 ----
    launch_mfma(nuB, WohT, N_NODESC, OCC, OCC, nullptr, 0, bufB, Qbuf, nullptr, stream);

    // ---- BN1 in place on x (d_out) ----
    hipLaunchKernelGGL(bn_stats_kernel, dim3(512), dim3(256), 0, stream, Qbuf, sums1, sq1, N_NODESC);
    hipLaunchKernelGGL(bn_apply_kernel, dim3((N_NODESC * OCC + 255) / 256), dim3(256), 0, stream,
                       Qbuf, sums1, sq1, g1, beta1, Qbuf, N_NODESC);

    // ---- FFN in chunks: y = x + gelu(x@W1+b1)@W2+b2 -> bufB ----
    for (int c0 = 0; c0 < N_NODESC; c0 += CH) {
        int mrows = (N_NODESC - c0 < CH) ? (N_NODESC - c0) : CH;
        const float* xc = Qbuf + (size_t)c0 * OCC;
        launch_cast(xc, xbC, mrows * OCC, stream);
        launch_mfma(xbC, W1T, mrows, 4 * OCC, OCC, b1, 1, nullptr, nullptr, ffnB, stream);
        launch_mfma(ffnB, W2T, mrows, OCC, 4 * OCC, b2, 0, xc, bufB + (size_t)c0 * OCC, nullptr, stream);
    }

    // ---- BN2 -> d_out ----
    hipLaunchKernelGGL(bn_stats_kernel, dim3(512), dim3(256), 0, stream, bufB, sums2, sq2, N_NODESC);
    hipLaunchKernelGGL(bn_apply_kernel, dim3((N_NODESC * OCC + 255) / 256), dim3(256), 0, stream,
                       bufB, sums2, sq2, g2, beta2, out, N_NODESC);
}